// Round 7
// baseline (112.219 us; speedup 1.0000x reference)
//
#include <hip/hip_runtime.h>
#include <math.h>

// Problem constants (from setup_inputs): B=2, V=10000, N=16, CIN=128, COUT=64
#define V_CNT 10000
#define NB 16
#define TQ 8           // queries per block (R7: 16->8 for 2x grid / more TLP)
#define BQ_TOTAL 20000 // B*V

// NOTE (R6 discovery): the harness re-poisons the 256MiB workspace with a
// fillBuffer EVERY timed iteration (~42us at HBM peak). That is a fixed cost
// inside dur_us we cannot remove; only prep+fold (+overhead) are attackable.

// ws float layout (weight scratch only):
//   [0, 2880)        W45T[kj][d]    (45 x 64, kj-major, float4-aligned rows)
//   [2880, 2925)     Wdir9[kj]      (45)
//   [2944, 3004)     FN[f*3+axis]   (20 x 3 face normals)
#define WS_W45T  0
#define WS_WD9   2880
#define WS_FN    2944

// Ps2T LDS row stride: 44 words = 176 B = 11*16 -> float4/float2-aligned rows.
#define PST 44

// _FTC permutation table (runtime-indexed -> device constant memory)
__device__ __constant__ int FTC_d[20][5] = {
  {1,4,0,2,3},{2,0,1,4,3},{3,1,0,4,2},{4,2,0,3,1},{0,3,1,2,4},
  {3,2,0,4,1},{4,3,0,2,1},{0,4,1,2,3},{1,0,2,4,3},{2,1,0,4,3},
  {4,0,1,3,2},{0,1,2,3,4},{1,2,0,3,4},{2,3,0,1,4},{3,4,0,1,2},
  {1,3,0,2,4},{0,2,1,3,4},{4,1,0,3,2},{3,0,1,4,2},{2,4,0,1,3}};

// faces grouped by color: RBYCOL[s][m] = m-th face r with FTC[r][0]==s.
__device__ __constant__ int RBYCOL_d[5][4] = {
  {4,7,11,16},{0,8,12,15},{1,9,13,19},{2,5,14,18},{3,6,10,17}};

// color of face f = _FTC[f][0] (compile-time folded in unrolled loops)
constexpr int COLF[20] = {1,2,3,4,0,3,4,0,1,2,4,0,1,2,3,1,0,4,3,2};

// w9[k][j] = w19[W9MAP[k][j]]  (the _build_kernel row construction)
// NOTE: rows k=0,1,8 have W9MAP[k][2]==[3]==[4] -> wdl[k*5+2..4] are EQUAL,
// so their dot contribution folds to wdl[k*5+2]*(e2+e3+e4).
constexpr int W9MAP[9][5] = {
  {0,1,2,2,2},{3,4,5,5,5},
  {9,10,11,12,13},{9,10,12,13,11},{9,10,13,11,12},
  {14,15,16,17,18},{14,15,17,18,16},{14,15,18,16,17},
  {6,7,8,8,8}};

__device__ __constant__ int FACES_d[20][3] = {
  {1,2,7},{1,3,7},{1,3,5},{1,4,5},{1,2,4},{2,7,8},{3,7,9},{3,5,11},{4,5,6},{2,4,10},
  {2,8,10},{7,8,9},{3,9,11},{5,6,11},{4,6,10},{0,8,10},{0,6,10},{0,6,11},{0,9,11},{0,8,9}};

#define PHI_F 1.61803398874989484820f
__device__ __constant__ float VS_d[12][3] = {
  {-1.f,PHI_F,0.f},{1.f,PHI_F,0.f},{-1.f,-PHI_F,0.f},{1.f,-PHI_F,0.f},
  {0.f,-1.f,PHI_F},{0.f,1.f,PHI_F},{0.f,-1.f,-PHI_F},{0.f,1.f,-PHI_F},
  {PHI_F,0.f,-1.f},{PHI_F,0.f,1.f},{-PHI_F,0.f,-1.f},{-PHI_F,0.f,1.f}};

__device__ __forceinline__ float fast_tanh(float x){
  // |x| <= 1 here (dot of unit vectors), no overflow concerns
  float e = __expf(2.0f * x);
  return 1.0f - 2.0f * __builtin_amdgcn_rcpf(e + 1.0f);
}

// ---------------------------------------------------------------------------
// Kernel 1: weight prep. Blocks 0..63: W45T[.][d] = w9(sum_c W[d,c,:]),
//           written TRANSPOSED (kj-major) so fold's Stage0 is a linear copy.
//           Block 64: Wdir9 = w9(sum_c W_dir[c,:]) + face normals.
// ---------------------------------------------------------------------------
__global__ __launch_bounds__(128) void prep_kernel(const float* __restrict__ W,
                                                   const float* __restrict__ Wdir,
                                                   float* __restrict__ ws){
  __shared__ float buf[128][20];   // pad 19->20 to break bank stride
  __shared__ float w19s[19];
  int d = blockIdx.x;   // 0..64
  int c = threadIdx.x;  // 0..127  (one per CIN)

  const float* src = (d < 64) ? (W + ((size_t)d*128 + c)*19) : (Wdir + (size_t)c*19);
  #pragma unroll
  for (int tt = 0; tt < 19; ++tt) buf[c][tt] = src[tt];

  if (d == 64 && c < 20){
    float x=0.f, y=0.f, z=0.f;
    #pragma unroll
    for (int vv=0; vv<3; ++vv){
      int vi = FACES_d[c][vv];
      x += VS_d[vi][0]; y += VS_d[vi][1]; z += VS_d[vi][2];
    }
    float inv = rsqrtf(x*x + y*y + z*z);
    ws[WS_FN + c*3 + 0] = x*inv;
    ws[WS_FN + c*3 + 1] = y*inv;
    ws[WS_FN + c*3 + 2] = z*inv;
  }
  __syncthreads();

  if (c < 19){
    float s = 0.f;
    for (int i = 0; i < 128; ++i) s += buf[i][c];
    w19s[c] = s;
  }
  __syncthreads();

  if (c < 45){
    int k = c / 5, j = c % 5;
    float v = w19s[W9MAP[k][j]];
    if (d < 64) ws[WS_W45T + c*64 + d] = v;     // transposed [kj][d]
    else        ws[WS_WD9  + c]        = v;
  }
}

// ---------------------------------------------------------------------------
// Kernel 2 (fused): per block: TQ=8 queries -> FINAL output.
//  R7: TQ 16->8. Same 320 threads, grid x2 (2500 blocks), LDS 32->21.5KB ->
//  6 blocks/CU resident (30 waves/CU, 7.5/SIMD vs 6.25) and per-thread
//  Phase-B n-loop HALVED (n split across 2 lanes) -> shorter latency chain.
//  Stage0: LINEAR copy ws->W45T LDS (conflict-free).
//  Phase A (128 thr = 8q x 16n): gather neighbor, normalize, 20 face dots
//          -> tanh -> 5 color sums  => de5s in LDS.
//  Phase B (320 thr = 8q x 5color x 4member x 2nhalf): lane 8-group
//          (ql,s,m,nh) owns face r=RBYCOL[s][m], n-range nh*8..nh*8+7;
//          acc[45] with 1-deep e-load pipeline; reduce over 8-lane group
//          (shfl_xor 1,2,4); sub==0 writes col to Ps2T[kj][col].
//  Phase C (320 thr = 16 dquad x 20 colpair): 64x45 @ 45x40 GEMM from LDS,
//          4x2 register tile; float2 stores along col.
//  __launch_bounds__(320) ONLY (R5: adding a min-waves floor caps VGPRs and
//  spills acc to scratch -- never floor a register-tight kernel).
// ---------------------------------------------------------------------------
__global__ __launch_bounds__(320) void fold_kernel(const int*   __restrict__ nbr,
                                                   const float* __restrict__ verts,
                                                   const float* __restrict__ ws,
                                                   float* __restrict__ out){
  __shared__ float de5s[TQ][NB][5];        // 2560 B
  __shared__ float Ps2T[45][PST];          // 7920 B   [kj][col], cols 0..39
  __shared__ float W45T[45][64];           // 11520 B  [kj][d]
  int t = threadIdx.x;
  int blockq0 = blockIdx.x * TQ;           // multiple of 8 -> never straddles b

  // ---- Stage0: linear, coalesced, conflict-free copy (2880 = 9*320) ----
  {
    float* wl = &W45T[0][0];
    #pragma unroll
    for (int sW = 0; sW < 9; ++sW) wl[t + sW*320] = ws[WS_W45T + t + sW*320];
  }

  // ---- Phase A ----
  if (t < TQ*NB){
    int ql = t >> 4;
    int n  = t & 15;
    int qg = blockq0 + ql;                       // 0..19999
    int q  = (qg >= V_CNT) ? (qg - V_CNT) : qg;
    int b0 = qg - q;                              // 0 or 10000
    int idx = nbr[qg*NB + n];
    float vx = verts[qg*3+0], vy = verts[qg*3+1], vz = verts[qg*3+2];
    const float* nv = verts + (size_t)(b0 + idx)*3;
    float dx = nv[0]-vx, dy = nv[1]-vy, dz = nv[2]-vz;
    float dd = dx*dx + dy*dy + dz*dz;
    float inv = (dd > 0.f) ? rsqrtf(dd) : 0.f;    // ref: d/max(||d||,1e-12); exact-0 -> 0
    dx *= inv; dy *= inv; dz *= inv;
    const float* fnp = ws + WS_FN;                // uniform -> scalar loads
    float s0=0.f, s1=0.f, s2=0.f, s3=0.f, s4=0.f;
    #pragma unroll
    for (int f = 0; f < 20; ++f){
      float x = fnp[f*3+0]*dx + fnp[f*3+1]*dy + fnp[f*3+2]*dz;
      float th = fast_tanh(x);
      if      (COLF[f]==0) s0 += th;
      else if (COLF[f]==1) s1 += th;
      else if (COLF[f]==2) s2 += th;
      else if (COLF[f]==3) s3 += th;
      else                 s4 += th;
    }
    de5s[ql][n][0]=s0; de5s[ql][n][1]=s1; de5s[ql][n][2]=s2;
    de5s[ql][n][3]=s3; de5s[ql][n][4]=s4;
  }
  __syncthreads();

  // ---- Phase B ----
  {
    int ql  = t / 40;            // 0..7
    int rem = t - ql*40;         // 0..39
    int s   = rem >> 3;          // color 0..4
    int sub = rem & 7;           // 0..7   (8-aligned lane group; 8|64 -> in-wave)
    int m   = sub >> 1;          // quad member 0..3
    int nh  = sub & 1;           // n-half 0..1
    int r   = RBYCOL_d[s][m];    // face handled by this lane
    int f0 = FTC_d[r][0], f1 = FTC_d[r][1], f2 = FTC_d[r][2],
        f3 = FTC_d[r][3], f4 = FTC_d[r][4];     // f0 == s by construction
    const float* de = &de5s[ql][nh*8][0];        // this lane's 8 n's

    float wdl[45];
    #pragma unroll
    for (int i = 0; i < 45; ++i) wdl[i] = ws[WS_WD9 + i];  // uniform -> SGPR
    float acc[45];
    #pragma unroll
    for (int i = 0; i < 45; ++i) acc[i] = 0.f;

    // explicit 1-deep software pipeline on the 5 e-loads
    float ne0 = de[f0], ne1 = de[f1], ne2 = de[f2], ne3 = de[f3], ne4 = de[f4];
    #pragma unroll
    for (int n = 0; n < 8; ++n){
      float e0 = ne0, e1 = ne1, e2 = ne2, e3 = ne3, e4 = ne4;
      if (n < 7){
        const float* dn = de + (n+1)*5;
        ne0 = dn[f0]; ne1 = dn[f1]; ne2 = dn[f2]; ne3 = dn[f3]; ne4 = dn[f4];
      }
      float e234 = e2 + e3 + e4;   // wdl[k*5+2..4] equal for k in {0,1,8}
      #pragma unroll
      for (int k = 0; k < 9; ++k){
        float a;
        if (k == 0 || k == 1 || k == 8)
          a = wdl[k*5+0]*e0 + wdl[k*5+1]*e1 + wdl[k*5+2]*e234;
        else
          a = wdl[k*5+0]*e0 + wdl[k*5+1]*e1 + wdl[k*5+2]*e2
            + wdl[k*5+3]*e3 + wdl[k*5+4]*e4;
        a = fmaxf(a, 0.f);                       // relu
        acc[k*5+0] += a * e0;
        acc[k*5+1] += a * e1;
        acc[k*5+2] += a * e2;
        acc[k*5+3] += a * e3;
        acc[k*5+4] += a * e4;
      }
    }
    // 8-lane reduction: n-halves (xor 1) then the 4 faces of this color
    // (xor 2, xor 4). Group is 8-aligned, 8 | 64 -> never crosses a wave.
    #pragma unroll
    for (int i = 0; i < 45; ++i){
      acc[i] += __shfl_xor(acc[i], 1);
      acc[i] += __shfl_xor(acc[i], 2);
      acc[i] += __shfl_xor(acc[i], 4);
    }
    if (sub == 0){
      int col = ql*5 + s;
      #pragma unroll
      for (int i = 0; i < 45; ++i) Ps2T[i][col] = acc[i];
    }
  }
  __syncthreads();

  // ---- Phase C: out[d, col] = sum_kj W45T[kj][d] * Ps2T[kj][col] ----
  {
    int dq = t / 20;             // 0..15 -> d0 = dq*4
    int cq = t - dq*20;          // 0..19 -> col0 = cq*2 (inner for coalescing)
    float a00=0,a01=0, a10=0,a11=0, a20=0,a21=0, a30=0,a31=0;
    #pragma unroll
    for (int kj = 0; kj < 45; ++kj){
      float4 w = *(const float4*)&W45T[kj][dq*4];
      float2 p = *(const float2*)&Ps2T[kj][cq*2];
      a00 += w.x*p.x; a01 += w.x*p.y;
      a10 += w.y*p.x; a11 += w.y*p.y;
      a20 += w.z*p.x; a21 += w.z*p.y;
      a30 += w.w*p.x; a31 += w.w*p.y;
    }
    int b   = (blockq0 >= V_CNT) ? 1 : 0;
    int lq0 = blockq0 - b*V_CNT;
    float* ob = out + (size_t)b*3200000 + (size_t)lq0*5 + cq*2;
    int d0 = dq*4;
    *(float2*)&ob[(size_t)(d0+0)*50000] = make_float2(a00,a01);
    *(float2*)&ob[(size_t)(d0+1)*50000] = make_float2(a10,a11);
    *(float2*)&ob[(size_t)(d0+2)*50000] = make_float2(a20,a21);
    *(float2*)&ob[(size_t)(d0+3)*50000] = make_float2(a30,a31);
  }
}

extern "C" void kernel_launch(void* const* d_in, const int* in_sizes, int n_in,
                              void* d_out, int out_size, void* d_ws, size_t ws_size,
                              hipStream_t stream){
  const int*   nbr   = (const int*)d_in[0];
  const float* verts = (const float*)d_in[1];
  const float* W     = (const float*)d_in[2];
  const float* Wdir  = (const float*)d_in[3];
  float* out = (float*)d_out;
  float* ws  = (float*)d_ws;           // ~12 KB weight scratch

  hipLaunchKernelGGL(prep_kernel, dim3(65), dim3(128), 0, stream, W, Wdir, ws);
  hipLaunchKernelGGL(fold_kernel, dim3(BQ_TOTAL/TQ), dim3(320), 0, stream, nbr, verts, ws, out);
}